// Round 9
// baseline (1679.589 us; speedup 1.0000x reference)
//
#include <hip/hip_runtime.h>

typedef _Float16 f16;
typedef _Float16 f16x2 __attribute__((ext_vector_type(2)));
typedef _Float16 f16x8 __attribute__((ext_vector_type(8)));
typedef float f32x4 __attribute__((ext_vector_type(4)));

#define DIM 256
#define HID 512

// ws element offsets (f16 units)
#define WSO_W1  0
#define WSO_W2  131072
#define WSO_WC1 262144
#define WSO_WC2 278528
#define PACK_TOTAL 279552

// LDS byte layout (dynamic smem): W1 kt5..7 | yst | hbuf(+h1) | k1..k4 state
#define LDS_W1   0         // 96 KB
#define LDS_YST  98304     // 8 KB
#define LDS_HB   106496    // 16 KB
#define LDS_K    122880    // 32 KB: [kid 0..3][pair 0..3][tid 0..511] f16x2
#define SMEM_BYTES 155648  // 152 KB -> 1 block/CU

#define MFMA(a, b, c) __builtin_amdgcn_mfma_f32_16x16x32_f16(a, b, c, 0, 0, 0)

// Pack weights into MFMA B-fragment order (16x16x32_f16):
// frag (kt,nt): lane l, elem j -> B[k = kt*32 + (l>>4)*8 + j][n = nt*16 + (l&15)]
__global__ void pack_weights(const float* __restrict__ W1, const float* __restrict__ W2,
                             const float* __restrict__ Wc1, const float* __restrict__ Wc2,
                             f16* __restrict__ ws) {
    int gid = blockIdx.x * 256 + threadIdx.x;
    if (gid >= PACK_TOTAL) return;
    if (gid < WSO_W2) {
        int g = gid;
        int j = g & 7, lane = (g >> 3) & 63, fi = g >> 9;
        int kt = fi >> 5, nt = fi & 31;                 // 8 x 32 frags
        int k = kt * 32 + ((lane >> 4) << 3) + j;
        int n = (nt << 4) + (lane & 15);
        ws[WSO_W1 + g] = (f16)W1[k * HID + n];
    } else if (gid < WSO_WC1) {
        int g = gid - WSO_W2;
        int j = g & 7, lane = (g >> 3) & 63, fi = g >> 9;
        int kt = fi >> 4, nt = fi & 15;                 // 16 x 16 frags
        int k = kt * 32 + ((lane >> 4) << 3) + j;
        int n = (nt << 4) + (lane & 15);
        ws[WSO_W2 + g] = (f16)W2[k * DIM + n];
    } else if (gid < WSO_WC2) {
        int g = gid - WSO_WC1;
        int j = g & 7, lane = (g >> 3) & 63, fi = g >> 9;
        int kt = fi >> 2, nt = fi & 3;                  // 8 x 4 frags
        int k = kt * 32 + ((lane >> 4) << 3) + j;
        int n = (nt << 4) + (lane & 15);
        ws[WSO_WC1 + g] = (f16)Wc1[k * 64 + n];
    } else {
        int g = gid - WSO_WC2;
        int j = g & 7, lane = (g >> 3) & 63, kt = g >> 9; // 2 frags
        int k = kt * 32 + ((lane >> 4) << 3) + j;
        int n = lane & 15;
        ws[WSO_WC2 + g] = (n < 10) ? (f16)Wc2[k * 10 + n] : (f16)0.0f;
    }
}

__device__ __forceinline__ float tanh_fast(float x) {
    float e = __expf(2.0f * x);
    return 1.0f - 2.0f * __builtin_amdgcn_rcpf(e + 1.0f);
}

// f(ys) = tanh(ys@W1+b1)@W2+b2 for the block's 16 rows. 8 waves.
// Wave w: m1 n-tiles 4w..4w+3 (HID), m2 n-tiles 2w,2w+1 (DIM).
// Thread slot: row = (lane>>4)*4+i ; col = w*32 + t*16 + (lane&15), t in 0..1
// W1 kt5-7 in LDS; W1 kt0-4 streamed (2-deep window); W2 kt0-15 streamed
// (4-slot rolling window). kout(t, f32x4) receives bias-added k values.
template <class FIN, class FOUT>
__device__ __forceinline__ void feval(FIN yin, FOUT kout,
        const f16* __restrict__ ws, const f16* w1lds, f16* yst, f16* hbuf,
        int lane, int w, const float b1c[4], const float b2c[2]) {
    const int cn   = lane & 15;
    const int rlo  = (lane >> 4) << 2;
    const int koff = (lane >> 4) << 3;

#define LDW1(KT, Q) (*(const f16x8*)(ws + WSO_W1 + ((((KT) * 32 + 4 * w + (Q)) << 9) + lane * 8)))
#define LDW2(KT, T) (*(const f16x8*)(ws + WSO_W2 + ((((KT) * 16 + 2 * w + (T)) << 9) + lane * 8)))

    // ---- write stage input, swizzled f16 [16][256] ----
    #pragma unroll
    for (int t = 0; t < 2; ++t)
        #pragma unroll
        for (int i = 0; i < 4; ++i) {
            int row = rlo + i;
            int col = w * 32 + t * 16 + cn;
            int idx = ((row << 8) + col) ^ ((row & 7) << 3);
            yst[idx] = (f16)yin(t, i);
        }
    __syncthreads();   // BARRIER_A

    // ---- W1 stream: 2-deep window (kt0, kt1 preloaded after barrier) ----
    f16x8 wA[4], wB[4];
    #pragma unroll
    for (int q = 0; q < 4; ++q) wA[q] = LDW1(0, q);
    #pragma unroll
    for (int q = 0; q < 4; ++q) wB[q] = LDW1(1, q);

    // ---- m1: h = ys @ W1 ; order 5(L),6(L),0(S),7(L),1(S),2(S),3(S),4(S) ----
    f32x4 acc[4];
    #pragma unroll
    for (int q = 0; q < 4; ++q) acc[q] = (f32x4){0.f, 0.f, 0.f, 0.f};

#define M1_LDS(KT) { \
        int aidx = ((cn << 8) + (KT) * 32 + koff) ^ ((cn & 7) << 3); \
        f16x8 af = *(const f16x8*)(yst + aidx); \
        _Pragma("unroll") \
        for (int q = 0; q < 4; ++q) { \
            f16x8 wf = *(const f16x8*)(w1lds + ((((KT) - 5) * 32 + 4 * w + q) << 9) + lane * 8); \
            acc[q] = MFMA(af, wf, acc[q]); } }
#define M1_STR(KT, WIN, RKT, DOREF) { \
        int aidx = ((cn << 8) + (KT) * 32 + koff) ^ ((cn & 7) << 3); \
        f16x8 af = *(const f16x8*)(yst + aidx); \
        f16x8 t0 = WIN[0], t1 = WIN[1], t2 = WIN[2], t3 = WIN[3]; \
        if (DOREF) { \
            WIN[0] = LDW1(RKT, 0); WIN[1] = LDW1(RKT, 1); \
            WIN[2] = LDW1(RKT, 2); WIN[3] = LDW1(RKT, 3); } \
        acc[0] = MFMA(af, t0, acc[0]); acc[1] = MFMA(af, t1, acc[1]); \
        acc[2] = MFMA(af, t2, acc[2]); acc[3] = MFMA(af, t3, acc[3]); }

    M1_LDS(5)
    M1_LDS(6)
    M1_STR(0, wA, 2, 1)
    M1_LDS(7)
    M1_STR(1, wB, 3, 1)
    M1_STR(2, wA, 4, 1)
    M1_STR(3, wB, 0, 0)
    M1_STR(4, wA, 0, 0)
#undef M1_LDS
#undef M1_STR

    // tanh -> swizzled hbuf [16][512]
    #pragma unroll
    for (int q = 0; q < 4; ++q) {
        int hcol = ((4 * w + q) << 4) + cn;
        #pragma unroll
        for (int i = 0; i < 4; ++i) {
            float th = tanh_fast(acc[q][i] + b1c[q]);
            int row = rlo + i;
            int idx = ((row << 9) + hcol) ^ ((row & 7) << 3);
            hbuf[idx] = (f16)th;
        }
    }
    __syncthreads();   // BARRIER_B

    // ---- m2: k = h @ W2 + b2 ; all 16 kt streamed, 4-slot rolling window ----
    f16x8 w2s[4][2];
    #pragma unroll
    for (int st = 0; st < 4; ++st) {
        w2s[st][0] = LDW2(st, 0);
        w2s[st][1] = LDW2(st, 1);
    }

    f32x4 acc2[2];
    acc2[0] = (f32x4){0.f, 0.f, 0.f, 0.f};
    acc2[1] = (f32x4){0.f, 0.f, 0.f, 0.f};

#define M2(KT) { \
        int aidx = ((cn << 9) + (KT) * 32 + koff) ^ ((cn & 7) << 3); \
        f16x8 af = *(const f16x8*)(hbuf + aidx); \
        f16x8 b0 = w2s[(KT) & 3][0], b1v = w2s[(KT) & 3][1]; \
        if ((KT) < 12) { \
            w2s[(KT) & 3][0] = LDW2((KT) + 4, 0); \
            w2s[(KT) & 3][1] = LDW2((KT) + 4, 1); } \
        acc2[0] = MFMA(af, b0, acc2[0]); \
        acc2[1] = MFMA(af, b1v, acc2[1]); }

    M2(0)  M2(1)  M2(2)  M2(3)
    M2(4)  M2(5)  M2(6)  M2(7)
    M2(8)  M2(9)  M2(10) M2(11)
    M2(12) M2(13) M2(14) M2(15)
#undef M2
#undef LDW1
#undef LDW2

    #pragma unroll
    for (int t = 0; t < 2; ++t) {
        f32x4 v = acc2[t];
        #pragma unroll
        for (int i = 0; i < 4; ++i) v[i] += b2c[t];
        kout(t, v);
    }
}

__launch_bounds__(512)
__global__ void ode_main(const float* __restrict__ x0, const float* __restrict__ tg,
                         const float* __restrict__ b1, const float* __restrict__ b2,
                         const float* __restrict__ bc1, const float* __restrict__ bc2,
                         const f16* __restrict__ ws, float* __restrict__ out) {
    extern __shared__ char smem[];
    f16* w1lds = (f16*)(smem + LDS_W1);
    f16* yst   = (f16*)(smem + LDS_YST);
    f16* hbuf  = (f16*)(smem + LDS_HB);
    f16* klds  = (f16*)(smem + LDS_K);

    const int tid  = threadIdx.x;
    const int lane = tid & 63;
    const int w    = tid >> 6;            // wave 0..7
    const int r0   = blockIdx.x * 16;
    const int cn   = lane & 15;
    const int rlo  = (lane >> 4) << 2;

    // ---- one-time: W1 kt5..7 into LDS (frag-linear, 96 KB) ----
    #pragma unroll
    for (int u = 0; u < 12; ++u) {
        int e = (u * 512 + tid) * 8;
        *(f16x8*)(w1lds + e) = *(const f16x8*)(ws + WSO_W1 + 81920 + e);
    }

    float b1c[4], b2c[2];
    #pragma unroll
    for (int q = 0; q < 4; ++q) b1c[q] = b1[((4 * w + q) << 4) + cn];
    #pragma unroll
    for (int t = 0; t < 2; ++t) b2c[t] = b2[((2 * w + t) << 4) + cn];

    // k1..k4 live in LDS (thread-private slots, no sync needed):
    //   addr(kid, pair) = ((kid*4 + pair) << 10) + tid*2   [f16 units]
    auto kput = [&](int kid, int t, f32x4 v) {
        f16x2 p0; p0[0] = (f16)v[0]; p0[1] = (f16)v[1];
        f16x2 p1; p1[0] = (f16)v[2]; p1[1] = (f16)v[3];
        *(f16x2*)(klds + (((kid << 2) + (t << 1) + 0) << 10) + tid * 2) = p0;
        *(f16x2*)(klds + (((kid << 2) + (t << 1) + 1) << 10) + tid * 2) = p1;
    };
    auto kget = [&](int kid, int t, int i) -> float {
        f16x2 p = *(const f16x2*)(klds + (((kid << 2) + (t << 1) + (i >> 1)) << 10) + tid * 2);
        return (float)p[i & 1];
    };

    // state: row = r0 + rlo + i, col = w*32 + t*16 + cn ; y f32, k5 packed f16x2
    float y[2][4];
    #pragma unroll
    for (int t = 0; t < 2; ++t)
        #pragma unroll
        for (int i = 0; i < 4; ++i)
            y[t][i] = x0[(r0 + rlo + i) * DIM + w * 32 + t * 16 + cn];

    __syncthreads();  // W1 LDS fill visible

    f16x2 k5p[2][2];
    float dt = 0.f;

#define K5GET(t, i) ((float)k5p[t][(i) >> 1][(i) & 1])

    for (int s = 0; s < 28; ++s) {
        if ((s & 3) == 0) { int iv = s >> 2; dt = (tg[iv + 1] - tg[iv]) * 0.25f; }

        feval([&](int t, int i) { return y[t][i]; },
              [&](int t, f32x4 v) { kput(0, t, v); },
              ws, w1lds, yst, hbuf, lane, w, b1c, b2c);
        feval([&](int t, int i) { return y[t][i] + dt * 0.2f * kget(0, t, i); },
              [&](int t, f32x4 v) { kput(1, t, v); },
              ws, w1lds, yst, hbuf, lane, w, b1c, b2c);
        feval([&](int t, int i) { return y[t][i] + dt * (0.075f * kget(0, t, i) + 0.225f * kget(1, t, i)); },
              [&](int t, f32x4 v) { kput(2, t, v); },
              ws, w1lds, yst, hbuf, lane, w, b1c, b2c);
        feval([&](int t, int i) { return y[t][i] + dt * ((44.f/45.f) * kget(0, t, i) + (-56.f/15.f) * kget(1, t, i)
                                                        + (32.f/9.f) * kget(2, t, i)); },
              [&](int t, f32x4 v) { kput(3, t, v); },
              ws, w1lds, yst, hbuf, lane, w, b1c, b2c);
        feval([&](int t, int i) { return y[t][i] + dt * ((19372.f/6561.f) * kget(0, t, i) + (-25360.f/2187.f) * kget(1, t, i)
                                                        + (64448.f/6561.f) * kget(2, t, i) + (-212.f/729.f) * kget(3, t, i)); },
              [&](int t, f32x4 v) {
                  k5p[t][0][0] = (f16)v[0]; k5p[t][0][1] = (f16)v[1];
                  k5p[t][1][0] = (f16)v[2]; k5p[t][1][1] = (f16)v[3];
              },
              ws, w1lds, yst, hbuf, lane, w, b1c, b2c);
        // stage 6: fold k6 straight into y (k6 never stored)
        feval([&](int t, int i) { return y[t][i] + dt * ((9017.f/3168.f) * kget(0, t, i) + (-355.f/33.f) * kget(1, t, i)
                                                        + (46732.f/5247.f) * kget(2, t, i) + (49.f/176.f) * kget(3, t, i)
                                                        + (-5103.f/18656.f) * K5GET(t, i)); },
              [&](int t, f32x4 v) {
                  #pragma unroll
                  for (int i = 0; i < 4; ++i)
                      y[t][i] += dt * ((35.f/384.f)    * kget(0, t, i) + (500.f/1113.f)  * kget(2, t, i)
                                     + (125.f/192.f)   * kget(3, t, i) + (-2187.f/6784.f) * K5GET(t, i)
                                     + (11.f/84.f)     * v[i]);
              },
              ws, w1lds, yst, hbuf, lane, w, b1c, b2c);
    }
#undef K5GET

    // ---------------- classifier head ----------------
    #pragma unroll
    for (int t = 0; t < 2; ++t)
        #pragma unroll
        for (int i = 0; i < 4; ++i) {
            int row = rlo + i;
            int col = w * 32 + t * 16 + cn;
            int idx = ((row << 8) + col) ^ ((row & 7) << 3);
            yst[idx] = (f16)y[t][i];
        }
    __syncthreads();

    // h1 = relu(y @ Wc1 + bc1): waves 0..3, one 16-col tile each; h1 in hbuf
    if (w < 4) {
        const int koff = (lane >> 4) << 3;
        f32x4 ha = (f32x4){0.f, 0.f, 0.f, 0.f};
        #pragma unroll
        for (int kt = 0; kt < 8; ++kt) {
            int aidx = ((cn << 8) + kt * 32 + koff) ^ ((cn & 7) << 3);
            f16x8 af = *(const f16x8*)(yst + aidx);
            f16x8 wf = *(const f16x8*)(ws + WSO_WC1 + (((kt * 4 + w) << 9) + lane * 8));
            ha = MFMA(af, wf, ha);
        }
        float bb = bc1[(w << 4) + cn];
        #pragma unroll
        for (int i = 0; i < 4; ++i) {
            float v = fmaxf(ha[i] + bb, 0.f);
            int row = rlo + i;
            int idx = ((row << 6) + (w << 4) + cn) ^ ((row & 7) << 3);
            hbuf[idx] = (f16)v;
        }
    }
    __syncthreads();

    // logits = h1 @ Wc2 + bc2 (packed cols 10..15 zero): wave 0
    if (w == 0) {
        const int koff = (lane >> 4) << 3;
        f32x4 acc = (f32x4){0.f, 0.f, 0.f, 0.f};
        #pragma unroll
        for (int kt = 0; kt < 2; ++kt) {
            int aidx = ((cn << 6) + kt * 32 + koff) ^ ((cn & 7) << 3);
            f16x8 af = *(const f16x8*)(hbuf + aidx);
            f16x8 wf = *(const f16x8*)(ws + WSO_WC2 + ((kt << 9) + lane * 8));
            acc = MFMA(af, wf, acc);
        }
        if (cn < 10) {
            float bb = bc2[cn];
            #pragma unroll
            for (int i = 0; i < 4; ++i)
                out[(r0 + rlo + i) * 10 + cn] = acc[i] + bb;
        }
    }
}

extern "C" void kernel_launch(void* const* d_in, const int* in_sizes, int n_in,
                              void* d_out, int out_size, void* d_ws, size_t ws_size,
                              hipStream_t stream) {
    const float* x0  = (const float*)d_in[0];
    const float* tg  = (const float*)d_in[1];
    const float* W1  = (const float*)d_in[2];
    const float* b1  = (const float*)d_in[3];
    const float* W2  = (const float*)d_in[4];
    const float* b2  = (const float*)d_in[5];
    const float* Wc1 = (const float*)d_in[6];
    const float* bc1 = (const float*)d_in[7];
    const float* Wc2 = (const float*)d_in[8];
    const float* bc2 = (const float*)d_in[9];
    f16* ws = (f16*)d_ws;
    float* out = (float*)d_out;

    hipFuncSetAttribute((const void*)ode_main,
                        hipFuncAttributeMaxDynamicSharedMemorySize, SMEM_BYTES);

    pack_weights<<<(PACK_TOTAL + 255) / 256, 256, 0, stream>>>(W1, W2, Wc1, Wc2, ws);
    ode_main<<<128, 512, SMEM_BYTES, stream>>>(x0, tg, b1, b2, bc1, bc2, ws, out);
}